// Round 1
// baseline (131.396 us; speedup 1.0000x reference)
//
#include <hip/hip_runtime.h>
#include <math.h>

#define NRAYS 512
#define NSAMP 64
#define NVIEW 2
#define IMH 480
#define IMW 640
#define NFEAT 256
#define XROW 272   // 265-dim x row padded: 16B-aligned, 2-way-bank stride
#define HROW 144   // 128-dim h1 row padded: 16B-aligned, 2-way-bank stride
#define ZNEAR 0.7f
#define ZFAR 1.5f

__global__ __launch_bounds__(256, 2)
void nerf_fused(const float* __restrict__ rayo,
                const float* __restrict__ rayd,
                const float* __restrict__ images,
                const float* __restrict__ intr,
                const float* __restrict__ einv,
                const float* __restrict__ feats,
                const float* __restrict__ W1,
                const float* __restrict__ b1,
                const float* __restrict__ W2,
                const float* __restrict__ b2,
                const float* __restrict__ Wr,
                const float* __restrict__ br,
                float* __restrict__ out)
{
    __shared__ float xb[NSAMP * XROW];        // x-matrix; h1 (64x144) overlays after L1
    __shared__ float partials[4][NSAMP][4];
    __shared__ float outacc[NSAMP][4];
    __shared__ int   s_off[NSAMP][4];
    __shared__ float s_wxy[NSAMP][2];
    __shared__ float s_cam[NSAMP][3];
    __shared__ float s_cdir[4];

    const int t = threadIdx.x;
    const int r = blockIdx.x;
    const int lane = t & 63;                                  // lane = sample index
    const int g = __builtin_amdgcn_readfirstlane(t >> 6);     // wave = channel slice
    constexpr float STEP = (ZFAR - ZNEAR) / (NSAMP - 1);

    outacc[t >> 2][t & 3] = 0.0f;

    const float ox = rayo[r*3+0], oy = rayo[r*3+1], oz = rayo[r*3+2];
    const float dx = rayd[r*3+0], dy = rayd[r*3+1], dz = rayd[r*3+2];

    for (int v = 0; v < NVIEW; ++v) {
        __syncthreads();
        // ---- per-sample projection prep (one thread per sample) ----
        if (t < NSAMP) {
            const int p = t;
            const float z = ZNEAR + p * STEP;
            const float wxp = ox + z*dx, wyp = oy + z*dy, wzp = oz + z*dz;
            const float* E = einv + v*16;
            const float cx = E[0]*wxp + E[1]*wyp + E[2]*wzp + E[3];
            const float cy = E[4]*wxp + E[5]*wyp + E[6]*wzp + E[7];
            const float cz = E[8]*wxp + E[9]*wyp + E[10]*wzp + E[11];
            const float cw = E[12]*wxp + E[13]*wyp + E[14]*wzp + E[15];
            const float* Km = intr + v*16;
            const float px = Km[0]*cx + Km[1]*cy + Km[2]*cz + Km[3]*cw;
            const float py = Km[4]*cx + Km[5]*cy + Km[6]*cz + Km[7]*cw;
            const float pz = Km[8]*cx + Km[9]*cy + Km[10]*cz + Km[11]*cw;
            const float inv = pz + 1e-8f;
            float fx = px / inv, fy = py / inv;
            fx = fminf(fmaxf(fx, 0.0f), (float)(IMW-1));
            fy = fminf(fmaxf(fy, 0.0f), (float)(IMH-1));
            const int x0 = (int)floorf(fx), y0 = (int)floorf(fy);
            const int x1 = min(x0+1, IMW-1), y1 = min(y0+1, IMH-1);
            const int base = v*IMH*IMW;
            s_off[p][0] = (base + y0*IMW + x0) * NFEAT;
            s_off[p][1] = (base + y0*IMW + x1) * NFEAT;
            s_off[p][2] = (base + y1*IMW + x0) * NFEAT;
            s_off[p][3] = (base + y1*IMW + x1) * NFEAT;
            s_wxy[p][0] = fx - (float)x0;
            s_wxy[p][1] = fy - (float)y0;
            s_cam[p][0] = cx; s_cam[p][1] = cy; s_cam[p][2] = cz;
            if (t == 0) {
                s_cdir[0] = E[0]*dx + E[1]*dy + E[2]*dz;
                s_cdir[1] = E[4]*dx + E[5]*dy + E[6]*dz;
                s_cdir[2] = E[8]*dx + E[9]*dy + E[10]*dz;
            }
        }
        __syncthreads();
        // ---- bilinear gather: 4 threads per sample, float4 chunks ----
        {
            const int s = t >> 2, k = t & 3;
            const int o00 = s_off[s][0], o01 = s_off[s][1];
            const int o10 = s_off[s][2], o11 = s_off[s][3];
            const float wxf = s_wxy[s][0], wyf = s_wxy[s][1];
            const float w00 = (1.f-wxf)*(1.f-wyf), w01 = wxf*(1.f-wyf);
            const float w10 = (1.f-wxf)*wyf,       w11 = wxf*wyf;
            float* xrow = xb + s * XROW;
            #pragma unroll
            for (int i = 0; i < 16; ++i) {
                const int c = i*16 + k*4;
                const float4 f00 = *reinterpret_cast<const float4*>(feats + o00 + c);
                const float4 f01 = *reinterpret_cast<const float4*>(feats + o01 + c);
                const float4 f10 = *reinterpret_cast<const float4*>(feats + o10 + c);
                const float4 f11 = *reinterpret_cast<const float4*>(feats + o11 + c);
                xrow[9+c+0] = w00*f00.x + w01*f01.x + w10*f10.x + w11*f11.x;
                xrow[9+c+1] = w00*f00.y + w01*f01.y + w10*f10.y + w11*f11.y;
                xrow[9+c+2] = w00*f00.z + w01*f01.z + w10*f10.z + w11*f11.z;
                xrow[9+c+3] = w00*f00.w + w01*f01.w + w10*f10.w + w11*f11.w;
            }
            if (k == 0) {
                const int i00 = (o00 >> 8) * 3, i01 = (o01 >> 8) * 3;
                const int i10 = (o10 >> 8) * 3, i11 = (o11 >> 8) * 3;
                #pragma unroll
                for (int ch = 0; ch < 3; ++ch) {
                    const float bl = w00*images[i00+ch] + w01*images[i01+ch]
                                   + w10*images[i10+ch] + w11*images[i11+ch];
                    xrow[6+ch] = 2.0f*bl - 1.0f;
                }
                xrow[0] = s_cam[s][0]; xrow[1] = s_cam[s][1]; xrow[2] = s_cam[s][2];
            } else if (k == 1) {
                xrow[3] = s_cdir[0]; xrow[4] = s_cdir[1]; xrow[5] = s_cdir[2];
            }
        }
        __syncthreads();
        // ---- layer 1: lane = sample; wave g computes channels [32g, 32g+32) ----
        // weights are wave-uniform -> s_load/SGPR operand; x via per-lane ds_read_b128
        float acc[32];
        #pragma unroll
        for (int jj = 0; jj < 32; ++jj) acc[jj] = 0.0f;
        {
            const float* __restrict__ w1g = W1 + g*32;
            const float* xrow = xb + lane * XROW;
            for (int d4 = 0; d4 < 66; ++d4) {
                const float4 xv = *reinterpret_cast<const float4*>(xrow + d4*4);
                const float xa[4] = {xv.x, xv.y, xv.z, xv.w};
                #pragma unroll
                for (int i = 0; i < 4; ++i) {
                    const float* __restrict__ wrow = w1g + (d4*4 + i)*128;
                    #pragma unroll
                    for (int jj = 0; jj < 32; ++jj)
                        acc[jj] = fmaf(xa[i], wrow[jj], acc[jj]);
                }
            }
            const float xt = xrow[264];
            const float* __restrict__ wrow = w1g + 264*128;
            #pragma unroll
            for (int jj = 0; jj < 32; ++jj)
                acc[jj] = fmaf(xt, wrow[jj], acc[jj]);
        }
        __syncthreads();
        // bias+relu, write h1 over the (dead) x-buffer
        {
            float* hrow = xb + lane*HROW + g*32;
            #pragma unroll
            for (int q = 0; q < 8; ++q) {
                float4 hv;
                hv.x = fmaxf(acc[q*4+0] + b1[g*32+q*4+0], 0.0f);
                hv.y = fmaxf(acc[q*4+1] + b1[g*32+q*4+1], 0.0f);
                hv.z = fmaxf(acc[q*4+2] + b1[g*32+q*4+2], 0.0f);
                hv.w = fmaxf(acc[q*4+3] + b1[g*32+q*4+3], 0.0f);
                *reinterpret_cast<float4*>(hrow + q*4) = hv;
            }
        }
        __syncthreads();
        // ---- layer 2 ----
        float acc2[32];
        #pragma unroll
        for (int jj = 0; jj < 32; ++jj) acc2[jj] = 0.0f;
        {
            const float* __restrict__ w2g = W2 + g*32;
            const float* hrow = xb + lane*HROW;
            for (int d4 = 0; d4 < 32; ++d4) {
                const float4 hv = *reinterpret_cast<const float4*>(hrow + d4*4);
                const float ha[4] = {hv.x, hv.y, hv.z, hv.w};
                #pragma unroll
                for (int i = 0; i < 4; ++i) {
                    const float* __restrict__ wrow = w2g + (d4*4 + i)*128;
                    #pragma unroll
                    for (int jj = 0; jj < 32; ++jj)
                        acc2[jj] = fmaf(ha[i], wrow[jj], acc2[jj]);
                }
            }
        }
        // ---- readout partials: bias+relu then dot with Wr over this wave's slice ----
        {
            float pk0=0.f, pk1=0.f, pk2=0.f, pk3=0.f;
            #pragma unroll
            for (int jj = 0; jj < 32; ++jj) {
                const float h2 = fmaxf(acc2[jj] + b2[g*32+jj], 0.0f);
                const float* __restrict__ wr = Wr + (g*32+jj)*4;
                pk0 = fmaf(h2, wr[0], pk0);
                pk1 = fmaf(h2, wr[1], pk1);
                pk2 = fmaf(h2, wr[2], pk2);
                pk3 = fmaf(h2, wr[3], pk3);
            }
            partials[g][lane][0] = pk0; partials[g][lane][1] = pk1;
            partials[g][lane][2] = pk2; partials[g][lane][3] = pk3;
        }
        __syncthreads();
        {   // accumulate over waves (and over views across the v-loop)
            const int s = t >> 2, k = t & 3;
            outacc[s][k] += partials[0][s][k] + partials[1][s][k]
                          + partials[2][s][k] + partials[3][s][k];
        }
    }
    __syncthreads();
    // ---- volumetric render: wave 0, lane = sample p ----
    if (t < NSAMP) {
        const int p = t;
        const float o0 = 0.5f*outacc[p][0] + br[0];
        const float o1 = 0.5f*outacc[p][1] + br[1];
        const float o2 = 0.5f*outacc[p][2] + br[2];
        const float o3 = 0.5f*outacc[p][3] + br[3];
        const float c0 = 1.0f/(1.0f + __expf(-o0));
        const float c1 = 1.0f/(1.0f + __expf(-o1));
        const float c2 = 1.0f/(1.0f + __expf(-o2));
        const float dens = fmaxf(o3, 0.0f);
        const float zp  = ZNEAR + p * STEP;
        const float zn  = ZNEAR + (p+1) * STEP;
        const float dlast = (ZNEAR + 63*STEP) - (ZNEAR + 62*STEP);
        const float dist = (p == NSAMP-1) ? dlast : (zn - zp);
        const float alpha = 1.0f - __expf(-dens*dist);
        float scan = 1.0f - alpha + 1e-10f;          // inclusive cumprod via shfl scan
        #pragma unroll
        for (int off = 1; off < 64; off <<= 1) {
            const float vsh = __shfl_up(scan, off, 64);
            if (p >= off) scan *= vsh;
        }
        float trans = __shfl_up(scan, 1, 64);        // exclusive
        if (p == 0) trans = 1.0f;
        const float w = alpha * trans;
        float s0 = w*c0, s1 = w*c1, s2 = w*c2, sd = w*zp;
        #pragma unroll
        for (int m = 32; m > 0; m >>= 1) {
            s0 += __shfl_xor(s0, m, 64);
            s1 += __shfl_xor(s1, m, 64);
            s2 += __shfl_xor(s2, m, 64);
            sd += __shfl_xor(sd, m, 64);
        }
        if (p == 0) {
            out[r*3+0] = s0; out[r*3+1] = s1; out[r*3+2] = s2;
            out[NRAYS*3 + r] = sd;
        }
    }
}

extern "C" void kernel_launch(void* const* d_in, const int* in_sizes, int n_in,
                              void* d_out, int out_size, void* d_ws, size_t ws_size,
                              hipStream_t stream) {
    const float* rayo   = (const float*)d_in[0];
    const float* rayd   = (const float*)d_in[1];
    const float* images = (const float*)d_in[2];
    const float* intr   = (const float*)d_in[3];
    const float* einv   = (const float*)d_in[4];
    const float* feats  = (const float*)d_in[5];
    const float* W1     = (const float*)d_in[6];
    const float* b1     = (const float*)d_in[7];
    const float* W2     = (const float*)d_in[8];
    const float* b2     = (const float*)d_in[9];
    const float* Wr     = (const float*)d_in[10];
    const float* br     = (const float*)d_in[11];
    float* out = (float*)d_out;
    hipLaunchKernelGGL(nerf_fused, dim3(NRAYS), dim3(256), 0, stream,
                       rayo, rayd, images, intr, einv, feats,
                       W1, b1, W2, b2, Wr, br, out);
}

// Round 2
// 115.759 us; speedup vs baseline: 1.1351x; 1.1351x over previous
//
#include <hip/hip_runtime.h>
#include <math.h>

#define NRAYS 512
#define NSAMP 64
#define NVIEW 2
#define IMH 480
#define IMW 640
#define NFEAT 256
#define XROW 268   // 265-dim x row, padded to 67 float4 slots (16B-aligned stride)
#define HROW 132   // 128-dim h1 row, 16B-aligned stride
#define ZNEAR 0.7f
#define ZFAR 1.5f

// Kernel A: one block per (ray, view). 512 threads = 8 waves; wave g owns
// output channels [16g, 16g+16). lane = sample. Weight addresses are
// wave-uniform -> scalar loads (SGPR operands); x/h via per-lane ds_read_b128.
__global__ __launch_bounds__(512, 4)
void nerf_mlp(const float* __restrict__ rayo,
              const float* __restrict__ rayd,
              const float* __restrict__ images,
              const float* __restrict__ intr,
              const float* __restrict__ einv,
              const float* __restrict__ feats,
              const float* __restrict__ W1,
              const float* __restrict__ b1,
              const float* __restrict__ W2,
              const float* __restrict__ b2,
              const float* __restrict__ Wr,
              float* __restrict__ wsout)
{
    __shared__ float xb[NSAMP * XROW];          // x-matrix; h1 (64xHROW) overlays after L1
    __shared__ float partials[8][NSAMP][4];
    __shared__ int   s_off[NSAMP][4];
    __shared__ float s_wxy[NSAMP][2];
    __shared__ float s_cam[NSAMP][4];
    __shared__ float s_cdir[4];

    const int t = threadIdx.x;
    const int bid = blockIdx.x;
    const int r = bid >> 1;
    const int v = bid & 1;
    const int lane = t & 63;                                  // sample index
    const int g = __builtin_amdgcn_readfirstlane(t >> 6);     // wave = 16-ch slice
    constexpr float STEP = (ZFAR - ZNEAR) / (NSAMP - 1);

    const float ox = rayo[r*3+0], oy = rayo[r*3+1], oz = rayo[r*3+2];
    const float dx = rayd[r*3+0], dy = rayd[r*3+1], dz = rayd[r*3+2];

    // ---- per-sample projection prep ----
    if (t < NSAMP) {
        const int p = t;
        const float z = ZNEAR + p * STEP;
        const float wxp = ox + z*dx, wyp = oy + z*dy, wzp = oz + z*dz;
        const float* E = einv + v*16;
        const float cx = E[0]*wxp + E[1]*wyp + E[2]*wzp + E[3];
        const float cy = E[4]*wxp + E[5]*wyp + E[6]*wzp + E[7];
        const float cz = E[8]*wxp + E[9]*wyp + E[10]*wzp + E[11];
        const float cw = E[12]*wxp + E[13]*wyp + E[14]*wzp + E[15];
        const float* Km = intr + v*16;
        const float px = Km[0]*cx + Km[1]*cy + Km[2]*cz + Km[3]*cw;
        const float py = Km[4]*cx + Km[5]*cy + Km[6]*cz + Km[7]*cw;
        const float pz = Km[8]*cx + Km[9]*cy + Km[10]*cz + Km[11]*cw;
        const float inv = pz + 1e-8f;
        float fx = px / inv, fy = py / inv;
        fx = fminf(fmaxf(fx, 0.0f), (float)(IMW-1));
        fy = fminf(fmaxf(fy, 0.0f), (float)(IMH-1));
        const int x0 = (int)floorf(fx), y0 = (int)floorf(fy);
        const int x1 = min(x0+1, IMW-1), y1 = min(y0+1, IMH-1);
        const int base = v*IMH*IMW;
        s_off[p][0] = (base + y0*IMW + x0) * NFEAT;
        s_off[p][1] = (base + y0*IMW + x1) * NFEAT;
        s_off[p][2] = (base + y1*IMW + x0) * NFEAT;
        s_off[p][3] = (base + y1*IMW + x1) * NFEAT;
        s_wxy[p][0] = fx - (float)x0;
        s_wxy[p][1] = fy - (float)y0;
        s_cam[p][0] = cx; s_cam[p][1] = cy; s_cam[p][2] = cz;
        if (t == 0) {
            s_cdir[0] = E[0]*dx + E[1]*dy + E[2]*dz;
            s_cdir[1] = E[4]*dx + E[5]*dy + E[6]*dz;
            s_cdir[2] = E[8]*dx + E[9]*dy + E[10]*dz;
        }
    }
    __syncthreads();

    // ---- bilinear gather: 8 threads per sample, float4 chunks ----
    {
        const int s = t >> 3, k = t & 7;
        const int o00 = s_off[s][0], o01 = s_off[s][1];
        const int o10 = s_off[s][2], o11 = s_off[s][3];
        const float wxf = s_wxy[s][0], wyf = s_wxy[s][1];
        const float w00 = (1.f-wxf)*(1.f-wyf), w01 = wxf*(1.f-wyf);
        const float w10 = (1.f-wxf)*wyf,       w11 = wxf*wyf;
        float* xrow = xb + s * XROW;
        #pragma unroll
        for (int i = 0; i < 8; ++i) {
            const int c = k*32 + i*4;
            const float4 f00 = *reinterpret_cast<const float4*>(feats + o00 + c);
            const float4 f01 = *reinterpret_cast<const float4*>(feats + o01 + c);
            const float4 f10 = *reinterpret_cast<const float4*>(feats + o10 + c);
            const float4 f11 = *reinterpret_cast<const float4*>(feats + o11 + c);
            xrow[9+c+0] = w00*f00.x + w01*f01.x + w10*f10.x + w11*f11.x;
            xrow[9+c+1] = w00*f00.y + w01*f01.y + w10*f10.y + w11*f11.y;
            xrow[9+c+2] = w00*f00.z + w01*f01.z + w10*f10.z + w11*f11.z;
            xrow[9+c+3] = w00*f00.w + w01*f01.w + w10*f10.w + w11*f11.w;
        }
        if (k == 0) {
            const int i00 = (o00 >> 8) * 3, i01 = (o01 >> 8) * 3;
            const int i10 = (o10 >> 8) * 3, i11 = (o11 >> 8) * 3;
            #pragma unroll
            for (int ch = 0; ch < 3; ++ch) {
                const float bl = w00*images[i00+ch] + w01*images[i01+ch]
                               + w10*images[i10+ch] + w11*images[i11+ch];
                xrow[6+ch] = 2.0f*bl - 1.0f;
            }
            xrow[0] = s_cam[s][0]; xrow[1] = s_cam[s][1]; xrow[2] = s_cam[s][2];
        } else if (k == 1) {
            xrow[3] = s_cdir[0]; xrow[4] = s_cdir[1]; xrow[5] = s_cdir[2];
        }
    }
    __syncthreads();

    // ---- layer 1: wave g -> channels [16g,16g+16), lane = sample ----
    const int cb = g * 16;
    float acc[16];
    #pragma unroll
    for (int jj = 0; jj < 16; ++jj) acc[jj] = 0.0f;
    {
        const float* __restrict__ w1g = W1 + cb;
        const float* xrow = xb + lane * XROW;
        for (int d4 = 0; d4 < 66; ++d4) {
            const float4 xv = *reinterpret_cast<const float4*>(xrow + d4*4);
            const float xa[4] = {xv.x, xv.y, xv.z, xv.w};
            #pragma unroll
            for (int i = 0; i < 4; ++i) {
                const float* __restrict__ wrow = w1g + (d4*4 + i)*128;
                #pragma unroll
                for (int jj = 0; jj < 16; ++jj)
                    acc[jj] = fmaf(xa[i], wrow[jj], acc[jj]);
            }
        }
        const float xt = xrow[264];
        const float* __restrict__ wrow = w1g + 264*128;
        #pragma unroll
        for (int jj = 0; jj < 16; ++jj)
            acc[jj] = fmaf(xt, wrow[jj], acc[jj]);
    }
    __syncthreads();
    // bias+relu, h1 overlays the dead x-buffer
    {
        float* hrow = xb + lane*HROW + cb;
        #pragma unroll
        for (int q = 0; q < 4; ++q) {
            float4 hv;
            hv.x = fmaxf(acc[q*4+0] + b1[cb+q*4+0], 0.0f);
            hv.y = fmaxf(acc[q*4+1] + b1[cb+q*4+1], 0.0f);
            hv.z = fmaxf(acc[q*4+2] + b1[cb+q*4+2], 0.0f);
            hv.w = fmaxf(acc[q*4+3] + b1[cb+q*4+3], 0.0f);
            *reinterpret_cast<float4*>(hrow + q*4) = hv;
        }
    }
    __syncthreads();

    // ---- layer 2 ----
    float acc2[16];
    #pragma unroll
    for (int jj = 0; jj < 16; ++jj) acc2[jj] = 0.0f;
    {
        const float* __restrict__ w2g = W2 + cb;
        const float* hrow = xb + lane*HROW;
        for (int d4 = 0; d4 < 32; ++d4) {
            const float4 hv = *reinterpret_cast<const float4*>(hrow + d4*4);
            const float ha[4] = {hv.x, hv.y, hv.z, hv.w};
            #pragma unroll
            for (int i = 0; i < 4; ++i) {
                const float* __restrict__ wrow = w2g + (d4*4 + i)*128;
                #pragma unroll
                for (int jj = 0; jj < 16; ++jj)
                    acc2[jj] = fmaf(ha[i], wrow[jj], acc2[jj]);
            }
        }
    }
    // ---- readout partials over this wave's 16 channels ----
    {
        float pk0=0.f, pk1=0.f, pk2=0.f, pk3=0.f;
        #pragma unroll
        for (int jj = 0; jj < 16; ++jj) {
            const float h2 = fmaxf(acc2[jj] + b2[cb+jj], 0.0f);
            const float* __restrict__ wr = Wr + (cb+jj)*4;
            pk0 = fmaf(h2, wr[0], pk0);
            pk1 = fmaf(h2, wr[1], pk1);
            pk2 = fmaf(h2, wr[2], pk2);
            pk3 = fmaf(h2, wr[3], pk3);
        }
        partials[g][lane][0] = pk0; partials[g][lane][1] = pk1;
        partials[g][lane][2] = pk2; partials[g][lane][3] = pk3;
    }
    __syncthreads();
    if (t < 256) {
        const int s = t >> 2, k = t & 3;
        float sum = 0.0f;
        #pragma unroll
        for (int gg = 0; gg < 8; ++gg) sum += partials[gg][s][k];
        wsout[(bid*NSAMP + s)*4 + k] = sum;
    }
}

// Kernel B: per-ray render. 1 wave per ray; lane = sample.
__global__ __launch_bounds__(64)
void nerf_render(const float* __restrict__ ws,
                 const float* __restrict__ br,
                 float* __restrict__ out)
{
    const int r = blockIdx.x;
    const int p = threadIdx.x;
    constexpr float STEP = (ZFAR - ZNEAR) / (NSAMP - 1);
    const float4 a = *reinterpret_cast<const float4*>(ws + ((r*2+0)*NSAMP + p)*4);
    const float4 b = *reinterpret_cast<const float4*>(ws + ((r*2+1)*NSAMP + p)*4);
    const float o0 = 0.5f*(a.x + b.x) + br[0];
    const float o1 = 0.5f*(a.y + b.y) + br[1];
    const float o2 = 0.5f*(a.z + b.z) + br[2];
    const float o3 = 0.5f*(a.w + b.w) + br[3];
    const float c0 = 1.0f/(1.0f + __expf(-o0));
    const float c1 = 1.0f/(1.0f + __expf(-o1));
    const float c2 = 1.0f/(1.0f + __expf(-o2));
    const float dens = fmaxf(o3, 0.0f);
    const float zp = ZNEAR + p * STEP;
    const float zn = ZNEAR + (p+1) * STEP;
    const float dlast = (ZNEAR + 63*STEP) - (ZNEAR + 62*STEP);
    const float dist = (p == NSAMP-1) ? dlast : (zn - zp);
    const float alpha = 1.0f - __expf(-dens*dist);
    float scan = 1.0f - alpha + 1e-10f;              // inclusive cumprod
    #pragma unroll
    for (int off = 1; off < 64; off <<= 1) {
        const float vsh = __shfl_up(scan, off, 64);
        if (p >= off) scan *= vsh;
    }
    float trans = __shfl_up(scan, 1, 64);            // exclusive
    if (p == 0) trans = 1.0f;
    const float w = alpha * trans;
    float s0 = w*c0, s1 = w*c1, s2 = w*c2, sd = w*zp;
    #pragma unroll
    for (int m = 32; m > 0; m >>= 1) {
        s0 += __shfl_xor(s0, m, 64);
        s1 += __shfl_xor(s1, m, 64);
        s2 += __shfl_xor(s2, m, 64);
        sd += __shfl_xor(sd, m, 64);
    }
    if (p == 0) {
        out[r*3+0] = s0; out[r*3+1] = s1; out[r*3+2] = s2;
        out[NRAYS*3 + r] = sd;
    }
}

extern "C" void kernel_launch(void* const* d_in, const int* in_sizes, int n_in,
                              void* d_out, int out_size, void* d_ws, size_t ws_size,
                              hipStream_t stream) {
    const float* rayo   = (const float*)d_in[0];
    const float* rayd   = (const float*)d_in[1];
    const float* images = (const float*)d_in[2];
    const float* intr   = (const float*)d_in[3];
    const float* einv   = (const float*)d_in[4];
    const float* feats  = (const float*)d_in[5];
    const float* W1     = (const float*)d_in[6];
    const float* b1     = (const float*)d_in[7];
    const float* W2     = (const float*)d_in[8];
    const float* b2     = (const float*)d_in[9];
    const float* Wr     = (const float*)d_in[10];
    const float* br     = (const float*)d_in[11];
    float* out = (float*)d_out;
    float* ws  = (float*)d_ws;

    hipLaunchKernelGGL(nerf_mlp, dim3(NRAYS*NVIEW), dim3(512), 0, stream,
                       rayo, rayd, images, intr, einv, feats,
                       W1, b1, W2, b2, Wr, ws);
    hipLaunchKernelGGL(nerf_render, dim3(NRAYS), dim3(64), 0, stream,
                       ws, br, out);
}